// Round 1
// baseline (379.977 us; speedup 1.0000x reference)
//
#include <hip/hip_runtime.h>
#include <math.h>

#define GELU(v) (0.5f * (v) * (1.0f + erff((v)*0.70710678118654752440f)))

// ---------------- Setup: fold/transpose weights --------------------------------
// fwe2[grp(4)][ic(16)][k(9)][o(8)]            : enc2 transposed    (4608)
// fwd1[grp(2)][ic(32)][phase(4)][tap(4)][o(8)]: dec1 up2-folded    (8192)
// fwd2[ic(16)][phase(4)][tap(4)]              : dec2 up2-folded    (256)
// Fold rule (nearest-up2 then 3x3): phase a rows -> a=0:{ky0->dy0, ky1,ky2->dy1},
// a=1:{ky0,ky1->dy0, ky2->dy1}; same for columns with b.
__global__ __launch_bounds__(256) void k_fold(const float* __restrict__ e2w,
                                              const float* __restrict__ d1w,
                                              const float* __restrict__ d2w,
                                              float* __restrict__ fwe2,
                                              float* __restrict__ fwd1,
                                              float* __restrict__ fwd2) {
  int i = blockIdx.x * 256 + threadIdx.x;
  if (i < 4608) {
    int o = i & 7, k = (i >> 3) % 9, ic = (i / 72) & 15, grp = i / 1152;
    fwe2[i] = e2w[((grp * 8 + o) * 16 + ic) * 9 + k];
  } else if (i < 12800) {
    int j = i - 4608;
    int o = j & 7, pt = (j >> 3) & 15, ic = (j >> 7) & 31, grp = j >> 12;
    int a = pt >> 3, b2 = (pt >> 2) & 1, dy = (pt >> 1) & 1, dx = pt & 1;
    const float* wsrc = d1w + ((grp * 8 + o) * 32 + ic) * 9;
    float s = 0.f;
    for (int ky = 0; ky < 3; ++ky) {
      int rm = (a == 0) ? (ky == 0 ? 0 : 1) : (ky == 2 ? 1 : 0);
      if (rm != dy) continue;
      for (int kx = 0; kx < 3; ++kx) {
        int cm = (b2 == 0) ? (kx == 0 ? 0 : 1) : (kx == 2 ? 1 : 0);
        if (cm == dx) s += wsrc[ky * 3 + kx];
      }
    }
    fwd1[j] = s;
  } else if (i < 13056) {
    int j = i - 12800;
    int pt = j & 15, ic = j >> 4;
    int a = pt >> 3, b2 = (pt >> 2) & 1, dy = (pt >> 1) & 1, dx = pt & 1;
    const float* wsrc = d2w + ic * 9;
    float s = 0.f;
    for (int ky = 0; ky < 3; ++ky) {
      int rm = (a == 0) ? (ky == 0 ? 0 : 1) : (ky == 2 ? 1 : 0);
      if (rm != dy) continue;
      for (int kx = 0; kx < 3; ++kx) {
        int cm = (b2 == 0) ? (kx == 0 ? 0 : 1) : (kx == 2 ? 1 : 0);
        if (cm == dx) s += wsrc[ky * 3 + kx];
      }
    }
    fwd2[j] = s;
  }
}

// ---------------- Kernel A: conv1 (1->16) + maxpool2 + gelu --------------------
__global__ __launch_bounds__(256) void k_enc1(const float* __restrict__ x,
                                              const float* __restrict__ w,
                                              const float* __restrict__ bias,
                                              float* __restrict__ h1) {
  int gid = blockIdx.x * 256 + threadIdx.x;
  int xx = gid & 127, yy = (gid >> 7) & 127, b = gid >> 14;
  const float* xp = x + (size_t)b * 65536;
  int r0 = 2 * yy - 1, c0 = 2 * xx - 1;
  float in[4][4];
#pragma unroll
  for (int i = 0; i < 4; ++i) {
    int r = r0 + i;
    bool rv = (unsigned)r < 256u;
#pragma unroll
    for (int j = 0; j < 4; ++j) {
      int c = c0 + j;
      in[i][j] = (rv && (unsigned)c < 256u) ? xp[r * 256 + c] : 0.0f;
    }
  }
  float* op = h1 + (size_t)b * 262144 + yy * 128 + xx;
#pragma unroll
  for (int oc = 0; oc < 16; ++oc) {
    const float* wp = w + oc * 9;  // uniform -> s_load
    float s00 = 0.f, s01 = 0.f, s10 = 0.f, s11 = 0.f;
#pragma unroll
    for (int ky = 0; ky < 3; ++ky)
#pragma unroll
      for (int kx = 0; kx < 3; ++kx) {
        float wv = wp[ky * 3 + kx];
        s00 = fmaf(in[ky][kx], wv, s00);
        s01 = fmaf(in[ky][kx + 1], wv, s01);
        s10 = fmaf(in[ky + 1][kx], wv, s10);
        s11 = fmaf(in[ky + 1][kx + 1], wv, s11);
      }
    float m = fmaxf(fmaxf(s00, s01), fmaxf(s10, s11)) + bias[oc];
    op[oc * 16384] = GELU(m);
  }
}

// ---------------- Kernel B: conv2 (16->32) + maxpool2 --------------------------
__global__ __launch_bounds__(256) void k_enc2(const float* __restrict__ h1,
                                              const float* __restrict__ fwe2,
                                              const float* __restrict__ bias,
                                              float* __restrict__ h2) {
  __shared__ float st[16 * 360];  // [ic][18 rows][20: evens 0-9, odds 10-19]
  int tid = threadIdx.x;
  int b = blockIdx.y;
  int Y0 = (blockIdx.x >> 3) * 8, X0 = (blockIdx.x & 7) * 8;
  int r_s = 2 * Y0 - 1, c_s = 2 * X0 - 1;
  const float* ip = h1 + (size_t)b * 262144;
  for (int i = tid; i < 5184; i += 256) {  // 16 ic x 18 x 18
    int ic = i / 324, rr = (i % 324) / 18, cc = i % 18;
    int r = r_s + rr, c = c_s + cc;
    float v = ((unsigned)r < 128u && (unsigned)c < 128u) ? ip[ic * 16384 + r * 128 + c] : 0.f;
    st[ic * 360 + rr * 20 + (cc & 1) * 10 + (cc >> 1)] = v;
  }
  __syncthreads();
  int lane = tid & 63;
  int grp = __builtin_amdgcn_readfirstlane(tid >> 6);
  int oc0 = grp * 8;
  int ty = lane >> 3, tx = lane & 7;
  float acc[4][8];
#pragma unroll
  for (int p = 0; p < 4; ++p)
#pragma unroll
    for (int o = 0; o < 8; ++o) acc[p][o] = 0.f;
  const float* wgrp = fwe2 + grp * 1152;  // scalar base
#pragma unroll 1
  for (int ic = 0; ic < 16; ++ic) {
    const float* t = st + ic * 360 + (2 * ty) * 20 + tx;
    float iv[4][4];
#pragma unroll
    for (int dy = 0; dy < 4; ++dy)
#pragma unroll
      for (int dx = 0; dx < 4; ++dx)
        iv[dy][dx] = t[dy * 20 + (dx & 1) * 10 + (dx >> 1)];
    const float* wp = wgrp + ic * 72;  // 72 floats, scalar loads
#pragma unroll
    for (int k = 0; k < 9; ++k) {
      int ky = k / 3, kx = k % 3;
#pragma unroll
      for (int o = 0; o < 8; ++o) {
        float wv = wp[k * 8 + o];
        acc[0][o] = fmaf(iv[ky][kx], wv, acc[0][o]);
        acc[1][o] = fmaf(iv[ky][kx + 1], wv, acc[1][o]);
        acc[2][o] = fmaf(iv[ky + 1][kx], wv, acc[2][o]);
        acc[3][o] = fmaf(iv[ky + 1][kx + 1], wv, acc[3][o]);
      }
    }
  }
  float* op = h2 + (size_t)b * 131072 + (Y0 + ty) * 64 + X0 + tx;
#pragma unroll
  for (int o = 0; o < 8; ++o) {
    float m = fmaxf(fmaxf(acc[0][o], acc[1][o]), fmaxf(acc[2][o], acc[3][o])) + bias[oc0 + o];
    op[(oc0 + o) * 4096] = m;
  }
}

// ---------------- Kernel C: fused VQ (full 512-code scan + quantize + loss) ----
// One block = 256 tokens (1/thread). Full codebook staged in LDS as 512 rows of
// 36 floats (9 float4): elements 0..31 = code, element 32 = -0.5*||c||^2,
// 33..35 pad (never used). argmin d  <=>  argmax (f.c - 0.5||c||^2).
// Scan reads are wave-uniform ds_read_b128 (broadcast, 0 bank conflicts),
// double-buffered 2 codes/iter so DS stays counted-wait pipelined (in-order DS
// lets the compiler emit partial lgkmcnt, unlike the old SMEM s_load path).
// LDS 73.75 KB -> exactly 2 blocks/CU (2 waves/SIMD); VALU-bound by design.
__global__ __launch_bounds__(256) void k_vq(float* __restrict__ h2,
                                            const float* __restrict__ cb,
                                            float* __restrict__ idxout,
                                            float* __restrict__ partial) {
  __shared__ float4 st4[4608];  // 512 rows x 9 float4
  __shared__ float sred[4];
  float* stf = (float*)st4;
  int tid = threadIdx.x;

  // token loads issued first so vmcnt overlaps the LDS staging + barriers
  int t = blockIdx.x * 256 + tid;
  size_t a = (size_t)(t >> 12) * 131072 + (t & 4095);
  float f[32];
#pragma unroll
  for (int c = 0; c < 32; ++c) f[c] = h2[a + c * 4096];

  // stage raw codebook rows (stride 9 float4)
  const float4* cb4 = (const float4*)cb;  // 512 rows x 8 float4
  for (int i = tid; i < 4096; i += 256) {
    int row = i >> 3, q = i & 7;
    st4[row * 9 + q] = cb4[i];
  }
  __syncthreads();
  // fold -0.5*||c||^2 into element 32 of each row
  for (int r = tid; r < 512; r += 256) {
    const float4* rp4 = st4 + r * 9;
    float s = 0.f;
#pragma unroll
    for (int q = 0; q < 8; ++q) {
      float4 v = rp4[q];
      s = fmaf(v.x, v.x, s); s = fmaf(v.y, v.y, s);
      s = fmaf(v.z, v.z, s); s = fmaf(v.w, v.w, s);
    }
    stf[r * 36 + 32] = -0.5f * s;
  }
  __syncthreads();

  float bestk = -3.4e38f;
  int bi = 0;
  float4 A[9], B[9];
#pragma unroll
  for (int q = 0; q < 9; ++q) A[q] = st4[q];  // row 0
#pragma unroll 1
  for (int j = 0; j < 512; j += 2) {
    // prefetch row j+1 -> B
    const float4* nb = st4 + (j + 1) * 9;
#pragma unroll
    for (int q = 0; q < 9; ++q) B[q] = nb[q];
    // compute row j from A
    {
      float aa = A[8].x, bb = 0.f;  // aa starts at -0.5*csq
#pragma unroll
      for (int q = 0; q < 8; ++q) {
        float4 v = A[q];
        aa = fmaf(v.x, f[4 * q + 0], aa);
        bb = fmaf(v.y, f[4 * q + 1], bb);
        aa = fmaf(v.z, f[4 * q + 2], aa);
        bb = fmaf(v.w, f[4 * q + 3], bb);
      }
      float key = aa + bb;
      if (key > bestk) { bestk = key; bi = j; }
    }
    // prefetch row j+2 -> A (wraps harmlessly at the end)
    const float4* na = st4 + ((j + 2) & 511) * 9;
#pragma unroll
    for (int q = 0; q < 9; ++q) A[q] = na[q];
    // compute row j+1 from B
    {
      float aa = B[8].x, bb = 0.f;
#pragma unroll
      for (int q = 0; q < 8; ++q) {
        float4 v = B[q];
        aa = fmaf(v.x, f[4 * q + 0], aa);
        bb = fmaf(v.y, f[4 * q + 1], bb);
        aa = fmaf(v.z, f[4 * q + 2], aa);
        bb = fmaf(v.w, f[4 * q + 3], bb);
      }
      float key = aa + bb;
      if (key > bestk) { bestk = key; bi = j + 1; }
    }
  }

  // quantize in place + commit loss
  const float* qp = stf + bi * 36;  // divergent LDS gather (one-time)
  float loss = 0.f;
#pragma unroll
  for (int c = 0; c < 32; ++c) {
    float qv = qp[c];
    float dd = qv - f[c];
    loss = fmaf(dd, dd, loss);
    h2[a + c * 4096] = qv;
  }
  idxout[t] = (float)bi;
#pragma unroll
  for (int off = 32; off > 0; off >>= 1) loss += __shfl_down(loss, off, 64);
  if ((tid & 63) == 0) sred[tid >> 6] = loss;
  __syncthreads();
  if (tid == 0) partial[blockIdx.x] = (sred[0] + sred[1]) + (sred[2] + sred[3]);
}

// ---------------- Kernel F: finalize commit loss (512 partials) ----------------
__global__ __launch_bounds__(256) void k_loss(const float* __restrict__ partial,
                                              float* __restrict__ lossout) {
  __shared__ float sred[4];
  int tid = threadIdx.x;
  float v = partial[tid] + partial[tid + 256];
#pragma unroll
  for (int off = 32; off > 0; off >>= 1) v += __shfl_down(v, off, 64);
  if ((tid & 63) == 0) sred[tid >> 6] = v;
  __syncthreads();
  if (tid == 0)
    lossout[0] = ((sred[0] + sred[1]) + (sred[2] + sred[3])) * (1.0f / 4194304.0f);
}

// ---------------- Kernel D: up2 + conv (32->16) + gelu, phase-folded -----------
__global__ __launch_bounds__(256) void k_dec1(const float* __restrict__ q,
                                              const float* __restrict__ fwd1,
                                              const float* __restrict__ bias,
                                              float* __restrict__ o) {
  __shared__ float st[32 * 200];  // [ic][10 rows][20]
  int tid = threadIdx.x;
  int b = blockIdx.y;
  int R0 = (blockIdx.x >> 2) * 8, C0 = (blockIdx.x & 3) * 16;
  const float* ip = q + (size_t)b * 131072;
  for (int i = tid; i < 5760; i += 256) {  // 32 ic x 10 x 18
    int ic = i / 180, rr = (i % 180) / 18, cc = i % 18;
    int r = R0 - 1 + rr, c = C0 - 1 + cc;
    st[ic * 200 + rr * 20 + cc] =
        ((unsigned)r < 64u && (unsigned)c < 64u) ? ip[ic * 4096 + r * 64 + c] : 0.f;
  }
  __syncthreads();
  int lane = tid & 63, wid = tid >> 6;
  int qx = wid & 1;
  int grp = __builtin_amdgcn_readfirstlane(wid >> 1);
  int ty = lane >> 3, tx = qx * 8 + (lane & 7);
  float acc[4][8];
#pragma unroll
  for (int p = 0; p < 4; ++p)
#pragma unroll
    for (int o2 = 0; o2 < 8; ++o2) acc[p][o2] = 0.f;
  const float* wb = fwd1 + grp * 4096;
#pragma unroll 1
  for (int ic = 0; ic < 32; ++ic) {
    const float* t = st + ic * 200 + ty * 20 + tx;
    float i3[3][3];
#pragma unroll
    for (int dy = 0; dy < 3; ++dy)
#pragma unroll
      for (int dx = 0; dx < 3; ++dx) i3[dy][dx] = t[dy * 20 + dx];
    const float* wp = wb + ic * 128;  // scalar loads
#pragma unroll
    for (int p = 0; p < 4; ++p) {
      int a = p >> 1, b2 = p & 1;
#pragma unroll
      for (int tp = 0; tp < 4; ++tp) {
        int dy = tp >> 1, dx = tp & 1;
        float iv = i3[a + dy][b2 + dx];
#pragma unroll
        for (int o2 = 0; o2 < 8; ++o2)
          acc[p][o2] = fmaf(iv, wp[(p * 4 + tp) * 8 + o2], acc[p][o2]);
      }
    }
  }
  int Y = 2 * (R0 + ty), X = 2 * (C0 + tx);
#pragma unroll
  for (int o2 = 0; o2 < 8; ++o2) {
    int oc = grp * 8 + o2;
    float bb = bias[oc];
    float* p = o + (size_t)b * 262144 + (size_t)oc * 16384 + Y * 128 + X;
    float2 r0v, r1v;
    r0v.x = GELU(acc[0][o2] + bb);
    r0v.y = GELU(acc[1][o2] + bb);
    r1v.x = GELU(acc[2][o2] + bb);
    r1v.y = GELU(acc[3][o2] + bb);
    *(float2*)p = r0v;
    *(float2*)(p + 128) = r1v;
  }
}

// ---------------- Kernel E: up2 + conv (16->1) + clip, phase-folded ------------
__global__ __launch_bounds__(256) void k_dec2(const float* __restrict__ d1,
                                              const float* __restrict__ fwd2,
                                              const float* __restrict__ bias,
                                              float* __restrict__ out) {
  __shared__ float st[16 * 360];  // [ic][18 rows][20]
  int tid = threadIdx.x;
  int b = blockIdx.y;
  int R0 = (blockIdx.x >> 3) * 16, C0 = (blockIdx.x & 7) * 16;
  const float* ip = d1 + (size_t)b * 262144;
  for (int i = tid; i < 5184; i += 256) {  // 16 ic x 18 x 18
    int ic = i / 324, rr = (i % 324) / 18, cc = i % 18;
    int r = R0 - 1 + rr, c = C0 - 1 + cc;
    st[ic * 360 + rr * 20 + cc] =
        ((unsigned)r < 128u && (unsigned)c < 128u) ? ip[ic * 16384 + r * 128 + c] : 0.f;
  }
  __syncthreads();
  int lane = tid & 63, wid = tid >> 6;
  int qy = wid >> 1, qx = wid & 1;
  int ty = qy * 8 + (lane >> 3), tx = qx * 8 + (lane & 7);
  float acc[4] = {0.f, 0.f, 0.f, 0.f};
#pragma unroll 1
  for (int ic = 0; ic < 16; ++ic) {
    const float* t = st + ic * 360 + ty * 20 + tx;
    float i3[3][3];
#pragma unroll
    for (int dy = 0; dy < 3; ++dy)
#pragma unroll
      for (int dx = 0; dx < 3; ++dx) i3[dy][dx] = t[dy * 20 + dx];
    const float* wp = fwd2 + ic * 16;  // scalar loads
#pragma unroll
    for (int p = 0; p < 4; ++p) {
      int a = p >> 1, b2 = p & 1;
#pragma unroll
      for (int tp = 0; tp < 4; ++tp) {
        int dy = tp >> 1, dx = tp & 1;
        acc[p] = fmaf(i3[a + dy][b2 + dx], wp[p * 4 + tp], acc[p]);
      }
    }
  }
  float bv = bias[0];
  int Y = 2 * (R0 + ty), X = 2 * (C0 + tx);
  float* op = out + (size_t)b * 65536 + Y * 256 + X;
  float2 r0v, r1v;
  r0v.x = fminf(1.0f, fmaxf(-1.0f, acc[0] + bv));
  r0v.y = fminf(1.0f, fmaxf(-1.0f, acc[1] + bv));
  r1v.x = fminf(1.0f, fmaxf(-1.0f, acc[2] + bv));
  r1v.y = fminf(1.0f, fmaxf(-1.0f, acc[3] + bv));
  *(float2*)op = r0v;
  *(float2*)(op + 256) = r1v;
}

extern "C" void kernel_launch(void* const* d_in, const int* in_sizes, int n_in,
                              void* d_out, int out_size, void* d_ws, size_t ws_size,
                              hipStream_t stream) {
  const float* x   = (const float*)d_in[0];
  const float* e1w = (const float*)d_in[1];
  const float* e1b = (const float*)d_in[2];
  const float* e2w = (const float*)d_in[3];
  const float* e2b = (const float*)d_in[4];
  const float* cb  = (const float*)d_in[5];
  const float* d1w = (const float*)d_in[6];
  const float* d1b = (const float*)d_in[7];
  const float* d2w = (const float*)d_in[8];
  const float* d2b = (const float*)d_in[9];

  float* out = (float*)d_out;
  float* y       = out;                       // [32,1,256,256] = 2097152
  float* idxout  = out + 2097152;             // [32,64,64]     = 131072 (as float)
  float* lossout = out + 2097152 + 131072;    // scalar

  float* ws = (float*)d_ws;
  float* h1      = ws;                        // [32,16,128,128] = 8388608 floats
  float* h2      = ws + 8388608;              // [32,32,64,64]   = 4194304 floats
  float* partial = ws + 12582912;             // 512 floats
  float* fwe2    = ws + 12583424;             // 4608
  float* fwd1    = ws + 12588032;             // 8192
  float* fwd2    = ws + 12596224;             // 256
  float* d1o     = h1;                        // dec1 output reuses h1 (after VQ)

  k_fold<<<dim3(51), 256, 0, stream>>>(e2w, d1w, d2w, fwe2, fwd1, fwd2);
  k_enc1<<<dim3(2048), 256, 0, stream>>>(x, e1w, e1b, h1);
  k_enc2<<<dim3(64, 32), 256, 0, stream>>>(h1, fwe2, e2b, h2);
  k_vq<<<dim3(512), 256, 0, stream>>>(h2, cb, idxout, partial);
  k_loss<<<dim3(1), 256, 0, stream>>>(partial, lossout);
  k_dec1<<<dim3(32, 32), 256, 0, stream>>>(h2, fwd1, d1b, d1o);
  k_dec2<<<dim3(64, 32), 256, 0, stream>>>(d1o, fwd2, d2b, y);
}

// Round 2
// 299.214 us; speedup vs baseline: 1.2699x; 1.2699x over previous
//
#include <hip/hip_runtime.h>
#include <math.h>

#define GELU(v) (0.5f * (v) * (1.0f + erff((v)*0.70710678118654752440f)))

// ---------------- Setup: fold/transpose weights --------------------------------
// fwe2[grp(4)][ic(16)][k(9)][o(8)]            : enc2 transposed    (4608)
// fwd1[grp(2)][ic(32)][phase(4)][tap(4)][o(8)]: dec1 up2-folded    (8192)
// fwd2[ic(16)][phase(4)][tap(4)]              : dec2 up2-folded    (256)
__global__ __launch_bounds__(256) void k_fold(const float* __restrict__ e2w,
                                              const float* __restrict__ d1w,
                                              const float* __restrict__ d2w,
                                              float* __restrict__ fwe2,
                                              float* __restrict__ fwd1,
                                              float* __restrict__ fwd2) {
  int i = blockIdx.x * 256 + threadIdx.x;
  if (i < 4608) {
    int o = i & 7, k = (i >> 3) % 9, ic = (i / 72) & 15, grp = i / 1152;
    fwe2[i] = e2w[((grp * 8 + o) * 16 + ic) * 9 + k];
  } else if (i < 12800) {
    int j = i - 4608;
    int o = j & 7, pt = (j >> 3) & 15, ic = (j >> 7) & 31, grp = j >> 12;
    int a = pt >> 3, b2 = (pt >> 2) & 1, dy = (pt >> 1) & 1, dx = pt & 1;
    const float* wsrc = d1w + ((grp * 8 + o) * 32 + ic) * 9;
    float s = 0.f;
    for (int ky = 0; ky < 3; ++ky) {
      int rm = (a == 0) ? (ky == 0 ? 0 : 1) : (ky == 2 ? 1 : 0);
      if (rm != dy) continue;
      for (int kx = 0; kx < 3; ++kx) {
        int cm = (b2 == 0) ? (kx == 0 ? 0 : 1) : (kx == 2 ? 1 : 0);
        if (cm == dx) s += wsrc[ky * 3 + kx];
      }
    }
    fwd1[j] = s;
  } else if (i < 13056) {
    int j = i - 12800;
    int pt = j & 15, ic = j >> 4;
    int a = pt >> 3, b2 = (pt >> 2) & 1, dy = (pt >> 1) & 1, dx = pt & 1;
    const float* wsrc = d2w + ic * 9;
    float s = 0.f;
    for (int ky = 0; ky < 3; ++ky) {
      int rm = (a == 0) ? (ky == 0 ? 0 : 1) : (ky == 2 ? 1 : 0);
      if (rm != dy) continue;
      for (int kx = 0; kx < 3; ++kx) {
        int cm = (b2 == 0) ? (kx == 0 ? 0 : 1) : (kx == 2 ? 1 : 0);
        if (cm == dx) s += wsrc[ky * 3 + kx];
      }
    }
    fwd2[j] = s;
  }
}

// ---------------- Kernel A: conv1 (1->16) + maxpool2 + gelu --------------------
__global__ __launch_bounds__(256) void k_enc1(const float* __restrict__ x,
                                              const float* __restrict__ w,
                                              const float* __restrict__ bias,
                                              float* __restrict__ h1) {
  int gid = blockIdx.x * 256 + threadIdx.x;
  int xx = gid & 127, yy = (gid >> 7) & 127, b = gid >> 14;
  const float* xp = x + (size_t)b * 65536;
  int r0 = 2 * yy - 1, c0 = 2 * xx - 1;
  float in[4][4];
#pragma unroll
  for (int i = 0; i < 4; ++i) {
    int r = r0 + i;
    bool rv = (unsigned)r < 256u;
#pragma unroll
    for (int j = 0; j < 4; ++j) {
      int c = c0 + j;
      in[i][j] = (rv && (unsigned)c < 256u) ? xp[r * 256 + c] : 0.0f;
    }
  }
  float* op = h1 + (size_t)b * 262144 + yy * 128 + xx;
#pragma unroll
  for (int oc = 0; oc < 16; ++oc) {
    const float* wp = w + oc * 9;  // uniform -> s_load
    float s00 = 0.f, s01 = 0.f, s10 = 0.f, s11 = 0.f;
#pragma unroll
    for (int ky = 0; ky < 3; ++ky)
#pragma unroll
      for (int kx = 0; kx < 3; ++kx) {
        float wv = wp[ky * 3 + kx];
        s00 = fmaf(in[ky][kx], wv, s00);
        s01 = fmaf(in[ky][kx + 1], wv, s01);
        s10 = fmaf(in[ky + 1][kx], wv, s10);
        s11 = fmaf(in[ky + 1][kx + 1], wv, s11);
      }
    float m = fmaxf(fmaxf(s00, s01), fmaxf(s10, s11)) + bias[oc];
    op[oc * 16384] = GELU(m);
  }
}

// ---------------- Kernel B: conv2 (16->32) + maxpool2 --------------------------
__global__ __launch_bounds__(256) void k_enc2(const float* __restrict__ h1,
                                              const float* __restrict__ fwe2,
                                              const float* __restrict__ bias,
                                              float* __restrict__ h2) {
  __shared__ float st[16 * 360];  // [ic][18 rows][20: evens 0-9, odds 10-19]
  int tid = threadIdx.x;
  int b = blockIdx.y;
  int Y0 = (blockIdx.x >> 3) * 8, X0 = (blockIdx.x & 7) * 8;
  int r_s = 2 * Y0 - 1, c_s = 2 * X0 - 1;
  const float* ip = h1 + (size_t)b * 262144;
  for (int i = tid; i < 5184; i += 256) {  // 16 ic x 18 x 18
    int ic = i / 324, rr = (i % 324) / 18, cc = i % 18;
    int r = r_s + rr, c = c_s + cc;
    float v = ((unsigned)r < 128u && (unsigned)c < 128u) ? ip[ic * 16384 + r * 128 + c] : 0.f;
    st[ic * 360 + rr * 20 + (cc & 1) * 10 + (cc >> 1)] = v;
  }
  __syncthreads();
  int lane = tid & 63;
  int grp = __builtin_amdgcn_readfirstlane(tid >> 6);
  int oc0 = grp * 8;
  int ty = lane >> 3, tx = lane & 7;
  float acc[4][8];
#pragma unroll
  for (int p = 0; p < 4; ++p)
#pragma unroll
    for (int o = 0; o < 8; ++o) acc[p][o] = 0.f;
  const float* wgrp = fwe2 + grp * 1152;  // scalar base
#pragma unroll 1
  for (int ic = 0; ic < 16; ++ic) {
    const float* t = st + ic * 360 + (2 * ty) * 20 + tx;
    float iv[4][4];
#pragma unroll
    for (int dy = 0; dy < 4; ++dy)
#pragma unroll
      for (int dx = 0; dx < 4; ++dx)
        iv[dy][dx] = t[dy * 20 + (dx & 1) * 10 + (dx >> 1)];
    const float* wp = wgrp + ic * 72;  // 72 floats, scalar loads
#pragma unroll
    for (int k = 0; k < 9; ++k) {
      int ky = k / 3, kx = k % 3;
#pragma unroll
      for (int o = 0; o < 8; ++o) {
        float wv = wp[k * 8 + o];
        acc[0][o] = fmaf(iv[ky][kx], wv, acc[0][o]);
        acc[1][o] = fmaf(iv[ky][kx + 1], wv, acc[1][o]);
        acc[2][o] = fmaf(iv[ky + 1][kx], wv, acc[2][o]);
        acc[3][o] = fmaf(iv[ky + 1][kx + 1], wv, acc[3][o]);
      }
    }
  }
  float* op = h2 + (size_t)b * 131072 + (Y0 + ty) * 64 + X0 + tx;
#pragma unroll
  for (int o = 0; o < 8; ++o) {
    float m = fmaxf(fmaxf(acc[0][o], acc[1][o]), fmaxf(acc[2][o], acc[3][o])) + bias[oc0 + o];
    op[(oc0 + o) * 4096] = m;
  }
}

// ---------------- Kernel C1: VQ distance scan over a 128-code chunk ------------
// 1 token/thread, grid = 4 chunks x 512 blocks -> 8 blocks/CU of TLP.
// Token floats pinned in VGPRs via opaque asm loads (compiler cannot remat).
// Codebook rows stream through the SCALAR pipe (uniform s_load) with an A/B
// ping-pong: touch 4 elems of current row first (forces the lgkmcnt(0) drain),
// THEN issue next row's loads, then the remaining 28 FMAs cover their latency.
// Exactly one row-group in flight at every wait point.
__global__ __launch_bounds__(256) void k_vq_chunk(const float* __restrict__ h2,
                                                  const float* __restrict__ cb,
                                                  float* __restrict__ dists,
                                                  int* __restrict__ idxs) {
  __shared__ float scsq[128];
  int tid = threadIdx.x;
  int chunk = blockIdx.x >> 9;
  int jbase = chunk << 7;
  if (tid < 128) {
    const float* row = cb + (size_t)(jbase + tid) * 32;
    float s = 0.f;
#pragma unroll
    for (int d = 0; d < 32; ++d) s = fmaf(row[d], row[d], s);
    scsq[tid] = s;
  }
  int t = (blockIdx.x & 511) * 256 + tid;
  size_t a = (size_t)(t >> 12) * 131072 + (t & 4095);
  float f[32];
#pragma unroll
  for (int c = 0; c < 32; ++c)
    asm volatile("global_load_dword %0, %1, off"
                 : "=v"(f[c])
                 : "v"(h2 + a + (size_t)c * 4096));
  __syncthreads();
  asm volatile("s_waitcnt vmcnt(0)" ::: "memory");
  __builtin_amdgcn_sched_barrier(0);

  float best = 3.4e38f;
  int bi = jbase;
  const float* rb = cb + (size_t)jbase * 32;
  float A[32], B[32], csqA, csqB;
#pragma unroll
  for (int q = 0; q < 32; ++q) A[q] = rb[q];
  csqA = scsq[0];
#pragma unroll 1
  for (int jl = 0; jl < 128; jl += 2) {
    // ---- row jl from A; prefetch row jl+1 -> B ----
    float s0 = A[0] * f[0], s1 = A[1] * f[1];
    s0 = fmaf(A[2], f[2], s0);
    s1 = fmaf(A[3], f[3], s1);
    __builtin_amdgcn_sched_barrier(0);
    {
      const float* nb = rb + (size_t)(jl + 1) * 32;
#pragma unroll
      for (int q = 0; q < 32; ++q) B[q] = nb[q];
      csqB = scsq[jl + 1];
    }
    __builtin_amdgcn_sched_barrier(0);
#pragma unroll
    for (int q = 4; q < 32; q += 2) {
      s0 = fmaf(A[q], f[q], s0);
      s1 = fmaf(A[q + 1], f[q + 1], s1);
    }
    float d0 = csqA - 2.0f * (s0 + s1);
    if (d0 < best) { best = d0; bi = jbase + jl; }
    // ---- row jl+1 from B; prefetch row jl+2 -> A ----
    s0 = B[0] * f[0]; s1 = B[1] * f[1];
    s0 = fmaf(B[2], f[2], s0);
    s1 = fmaf(B[3], f[3], s1);
    __builtin_amdgcn_sched_barrier(0);
    {
      const float* na = rb + (size_t)((jl + 2) & 127) * 32;  // wrap: stays in-bounds
#pragma unroll
      for (int q = 0; q < 32; ++q) A[q] = na[q];
      csqA = scsq[(jl + 2) & 127];
    }
    __builtin_amdgcn_sched_barrier(0);
#pragma unroll
    for (int q = 4; q < 32; q += 2) {
      s0 = fmaf(B[q], f[q], s0);
      s1 = fmaf(B[q + 1], f[q + 1], s1);
    }
    float d1 = csqB - 2.0f * (s0 + s1);
    if (d1 < best) { best = d1; bi = jbase + jl + 1; }
  }
  size_t cbase = (size_t)chunk * 131072;
  dists[cbase + t] = best;
  idxs[cbase + t] = bi;
}

// ---------------- Kernel C2: merge 4 chunk candidates, quantize, loss ----------
__global__ __launch_bounds__(256) void k_vq_merge(float* __restrict__ h2,
                                                  const float* __restrict__ cb,
                                                  const float* __restrict__ dists,
                                                  const int* __restrict__ idxs,
                                                  float* __restrict__ idxout,
                                                  float* __restrict__ partial) {
  __shared__ float sred[4];
  int tid = threadIdx.x;
  int t = blockIdx.x * 256 + tid;
  float bd = dists[t];
  int bi = idxs[t];
#pragma unroll
  for (int k = 1; k < 4; ++k) {
    float dk = dists[(size_t)k * 131072 + t];
    int ik = idxs[(size_t)k * 131072 + t];
    if (dk < bd) { bd = dk; bi = ik; }
  }
  size_t a = (size_t)(t >> 12) * 131072 + (t & 4095);
  const float* q = cb + (size_t)bi * 32;
  float loss = 0.f;
#pragma unroll
  for (int c = 0; c < 32; ++c) {
    float f = h2[a + c * 4096];
    float qv = q[c];
    h2[a + c * 4096] = qv;
    float dd = qv - f;
    loss = fmaf(dd, dd, loss);
  }
  idxout[t] = (float)bi;
#pragma unroll
  for (int off = 32; off > 0; off >>= 1) loss += __shfl_down(loss, off, 64);
  if ((tid & 63) == 0) sred[tid >> 6] = loss;
  __syncthreads();
  if (tid == 0) partial[blockIdx.x] = (sred[0] + sred[1]) + (sred[2] + sred[3]);
}

// ---------------- Kernel F: finalize commit loss (512 partials) ----------------
__global__ __launch_bounds__(256) void k_loss(const float* __restrict__ partial,
                                              float* __restrict__ lossout) {
  __shared__ float sred[4];
  int tid = threadIdx.x;
  float v = partial[tid] + partial[tid + 256];
#pragma unroll
  for (int off = 32; off > 0; off >>= 1) v += __shfl_down(v, off, 64);
  if ((tid & 63) == 0) sred[tid >> 6] = v;
  __syncthreads();
  if (tid == 0)
    lossout[0] = ((sred[0] + sred[1]) + (sred[2] + sred[3])) * (1.0f / 4194304.0f);
}

// ---------------- Kernel D: up2 + conv (32->16) + gelu, phase-folded -----------
__global__ __launch_bounds__(256) void k_dec1(const float* __restrict__ q,
                                              const float* __restrict__ fwd1,
                                              const float* __restrict__ bias,
                                              float* __restrict__ o) {
  __shared__ float st[32 * 200];  // [ic][10 rows][20]
  int tid = threadIdx.x;
  int b = blockIdx.y;
  int R0 = (blockIdx.x >> 2) * 8, C0 = (blockIdx.x & 3) * 16;
  const float* ip = q + (size_t)b * 131072;
  for (int i = tid; i < 5760; i += 256) {  // 32 ic x 10 x 18
    int ic = i / 180, rr = (i % 180) / 18, cc = i % 18;
    int r = R0 - 1 + rr, c = C0 - 1 + cc;
    st[ic * 200 + rr * 20 + cc] =
        ((unsigned)r < 64u && (unsigned)c < 64u) ? ip[ic * 4096 + r * 64 + c] : 0.f;
  }
  __syncthreads();
  int lane = tid & 63, wid = tid >> 6;
  int qx = wid & 1;
  int grp = __builtin_amdgcn_readfirstlane(wid >> 1);
  int ty = lane >> 3, tx = qx * 8 + (lane & 7);
  float acc[4][8];
#pragma unroll
  for (int p = 0; p < 4; ++p)
#pragma unroll
    for (int o2 = 0; o2 < 8; ++o2) acc[p][o2] = 0.f;
  const float* wb = fwd1 + grp * 4096;
#pragma unroll 1
  for (int ic = 0; ic < 32; ++ic) {
    const float* t = st + ic * 200 + ty * 20 + tx;
    float i3[3][3];
#pragma unroll
    for (int dy = 0; dy < 3; ++dy)
#pragma unroll
      for (int dx = 0; dx < 3; ++dx) i3[dy][dx] = t[dy * 20 + dx];
    const float* wp = wb + ic * 128;  // scalar loads
#pragma unroll
    for (int p = 0; p < 4; ++p) {
      int a = p >> 1, b2 = p & 1;
#pragma unroll
      for (int tp = 0; tp < 4; ++tp) {
        int dy = tp >> 1, dx = tp & 1;
        float iv = i3[a + dy][b2 + dx];
#pragma unroll
        for (int o2 = 0; o2 < 8; ++o2)
          acc[p][o2] = fmaf(iv, wp[(p * 4 + tp) * 8 + o2], acc[p][o2]);
      }
    }
  }
  int Y = 2 * (R0 + ty), X = 2 * (C0 + tx);
#pragma unroll
  for (int o2 = 0; o2 < 8; ++o2) {
    int oc = grp * 8 + o2;
    float bb = bias[oc];
    float* p = o + (size_t)b * 262144 + (size_t)oc * 16384 + Y * 128 + X;
    float2 r0v, r1v;
    r0v.x = GELU(acc[0][o2] + bb);
    r0v.y = GELU(acc[1][o2] + bb);
    r1v.x = GELU(acc[2][o2] + bb);
    r1v.y = GELU(acc[3][o2] + bb);
    *(float2*)p = r0v;
    *(float2*)(p + 128) = r1v;
  }
}

// ---------------- Kernel E: up2 + conv (16->1) + clip, phase-folded ------------
__global__ __launch_bounds__(256) void k_dec2(const float* __restrict__ d1,
                                              const float* __restrict__ fwd2,
                                              const float* __restrict__ bias,
                                              float* __restrict__ out) {
  __shared__ float st[16 * 360];  // [ic][18 rows][20]
  int tid = threadIdx.x;
  int b = blockIdx.y;
  int R0 = (blockIdx.x >> 3) * 16, C0 = (blockIdx.x & 7) * 16;
  const float* ip = d1 + (size_t)b * 262144;
  for (int i = tid; i < 5184; i += 256) {  // 16 ic x 18 x 18
    int ic = i / 324, rr = (i % 324) / 18, cc = i % 18;
    int r = R0 - 1 + rr, c = C0 - 1 + cc;
    st[ic * 360 + rr * 20 + cc] =
        ((unsigned)r < 128u && (unsigned)c < 128u) ? ip[ic * 16384 + r * 128 + c] : 0.f;
  }
  __syncthreads();
  int lane = tid & 63, wid = tid >> 6;
  int qy = wid >> 1, qx = wid & 1;
  int ty = qy * 8 + (lane >> 3), tx = qx * 8 + (lane & 7);
  float acc[4] = {0.f, 0.f, 0.f, 0.f};
#pragma unroll 1
  for (int ic = 0; ic < 16; ++ic) {
    const float* t = st + ic * 360 + ty * 20 + tx;
    float i3[3][3];
#pragma unroll
    for (int dy = 0; dy < 3; ++dy)
#pragma unroll
      for (int dx = 0; dx < 3; ++dx) i3[dy][dx] = t[dy * 20 + dx];
    const float* wp = fwd2 + ic * 16;  // scalar loads
#pragma unroll
    for (int p = 0; p < 4; ++p) {
      int a = p >> 1, b2 = p & 1;
#pragma unroll
      for (int tp = 0; tp < 4; ++tp) {
        int dy = tp >> 1, dx = tp & 1;
        acc[p] = fmaf(i3[a + dy][b2 + dx], wp[p * 4 + tp], acc[p]);
      }
    }
  }
  float bv = bias[0];
  int Y = 2 * (R0 + ty), X = 2 * (C0 + tx);
  float* op = out + (size_t)b * 65536 + Y * 256 + X;
  float2 r0v, r1v;
  r0v.x = fminf(1.0f, fmaxf(-1.0f, acc[0] + bv));
  r0v.y = fminf(1.0f, fmaxf(-1.0f, acc[1] + bv));
  r1v.x = fminf(1.0f, fmaxf(-1.0f, acc[2] + bv));
  r1v.y = fminf(1.0f, fmaxf(-1.0f, acc[3] + bv));
  *(float2*)op = r0v;
  *(float2*)(op + 256) = r1v;
}

extern "C" void kernel_launch(void* const* d_in, const int* in_sizes, int n_in,
                              void* d_out, int out_size, void* d_ws, size_t ws_size,
                              hipStream_t stream) {
  const float* x   = (const float*)d_in[0];
  const float* e1w = (const float*)d_in[1];
  const float* e1b = (const float*)d_in[2];
  const float* e2w = (const float*)d_in[3];
  const float* e2b = (const float*)d_in[4];
  const float* cb  = (const float*)d_in[5];
  const float* d1w = (const float*)d_in[6];
  const float* d1b = (const float*)d_in[7];
  const float* d2w = (const float*)d_in[8];
  const float* d2b = (const float*)d_in[9];

  float* out = (float*)d_out;
  float* y       = out;                       // [32,1,256,256] = 2097152
  float* idxout  = out + 2097152;             // [32,64,64]     = 131072 (as float)
  float* lossout = out + 2097152 + 131072;    // scalar

  float* ws = (float*)d_ws;
  float* h1      = ws;                        // [32,16,128,128] = 8388608 floats
  float* h2      = ws + 8388608;              // [32,32,64,64]   = 4194304 floats
  float* partial = ws + 12582912;             // 512 floats
  float* fwe2    = ws + 12583424;             // 4608
  float* fwd1    = ws + 12588032;             // 8192
  float* fwd2    = ws + 12596224;             // 256
  // VQ chunk outputs reuse the (dead-after-enc2) h1 region:
  float* dists   = ws;                        // 4 x 131072 floats
  int*   idxs    = (int*)(ws + 524288);       // 4 x 131072 ints
  float* d1o     = h1;                        // dec1 output reuses h1 (after merge)

  k_fold<<<dim3(51), 256, 0, stream>>>(e2w, d1w, d2w, fwe2, fwd1, fwd2);
  k_enc1<<<dim3(2048), 256, 0, stream>>>(x, e1w, e1b, h1);
  k_enc2<<<dim3(64, 32), 256, 0, stream>>>(h1, fwe2, e2b, h2);
  k_vq_chunk<<<dim3(2048), 256, 0, stream>>>(h2, cb, dists, idxs);
  k_vq_merge<<<dim3(512), 256, 0, stream>>>(h2, cb, dists, idxs, idxout, partial);
  k_loss<<<dim3(1), 256, 0, stream>>>(partial, lossout);
  k_dec1<<<dim3(32, 32), 256, 0, stream>>>(h2, fwd1, d1b, d1o);
  k_dec2<<<dim3(64, 32), 256, 0, stream>>>(d1o, fwd2, d2b, y);
}

// Round 3
// 298.736 us; speedup vs baseline: 1.2720x; 1.0016x over previous
//
#include <hip/hip_runtime.h>
#include <math.h>

#define GELU(v) (0.5f * (v) * (1.0f + erff((v)*0.70710678118654752440f)))

// ---------------- Setup: fold/transpose weights --------------------------------
// fwe2[grp(4)][ic(16)][k(9)][o(8)]            : enc2 transposed    (4608)
// fwd1[grp(2)][ic(32)][phase(4)][tap(4)][o(8)]: dec1 up2-folded    (8192)
// fwd2[ic(16)][phase(4)][tap(4)]              : dec2 up2-folded    (256)
__global__ __launch_bounds__(256) void k_fold(const float* __restrict__ e2w,
                                              const float* __restrict__ d1w,
                                              const float* __restrict__ d2w,
                                              float* __restrict__ fwe2,
                                              float* __restrict__ fwd1,
                                              float* __restrict__ fwd2) {
  int i = blockIdx.x * 256 + threadIdx.x;
  if (i < 4608) {
    int o = i & 7, k = (i >> 3) % 9, ic = (i / 72) & 15, grp = i / 1152;
    fwe2[i] = e2w[((grp * 8 + o) * 16 + ic) * 9 + k];
  } else if (i < 12800) {
    int j = i - 4608;
    int o = j & 7, pt = (j >> 3) & 15, ic = (j >> 7) & 31, grp = j >> 12;
    int a = pt >> 3, b2 = (pt >> 2) & 1, dy = (pt >> 1) & 1, dx = pt & 1;
    const float* wsrc = d1w + ((grp * 8 + o) * 32 + ic) * 9;
    float s = 0.f;
    for (int ky = 0; ky < 3; ++ky) {
      int rm = (a == 0) ? (ky == 0 ? 0 : 1) : (ky == 2 ? 1 : 0);
      if (rm != dy) continue;
      for (int kx = 0; kx < 3; ++kx) {
        int cm = (b2 == 0) ? (kx == 0 ? 0 : 1) : (kx == 2 ? 1 : 0);
        if (cm == dx) s += wsrc[ky * 3 + kx];
      }
    }
    fwd1[j] = s;
  } else if (i < 13056) {
    int j = i - 12800;
    int pt = j & 15, ic = j >> 4;
    int a = pt >> 3, b2 = (pt >> 2) & 1, dy = (pt >> 1) & 1, dx = pt & 1;
    const float* wsrc = d2w + ic * 9;
    float s = 0.f;
    for (int ky = 0; ky < 3; ++ky) {
      int rm = (a == 0) ? (ky == 0 ? 0 : 1) : (ky == 2 ? 1 : 0);
      if (rm != dy) continue;
      for (int kx = 0; kx < 3; ++kx) {
        int cm = (b2 == 0) ? (kx == 0 ? 0 : 1) : (kx == 2 ? 1 : 0);
        if (cm == dx) s += wsrc[ky * 3 + kx];
      }
    }
    fwd2[j] = s;
  }
}

// ---------------- Kernel A: conv1 (1->16) + maxpool2 + gelu --------------------
__global__ __launch_bounds__(256) void k_enc1(const float* __restrict__ x,
                                              const float* __restrict__ w,
                                              const float* __restrict__ bias,
                                              float* __restrict__ h1) {
  int gid = blockIdx.x * 256 + threadIdx.x;
  int xx = gid & 127, yy = (gid >> 7) & 127, b = gid >> 14;
  const float* xp = x + (size_t)b * 65536;
  int r0 = 2 * yy - 1, c0 = 2 * xx - 1;
  float in[4][4];
#pragma unroll
  for (int i = 0; i < 4; ++i) {
    int r = r0 + i;
    bool rv = (unsigned)r < 256u;
#pragma unroll
    for (int j = 0; j < 4; ++j) {
      int c = c0 + j;
      in[i][j] = (rv && (unsigned)c < 256u) ? xp[r * 256 + c] : 0.0f;
    }
  }
  float* op = h1 + (size_t)b * 262144 + yy * 128 + xx;
#pragma unroll
  for (int oc = 0; oc < 16; ++oc) {
    const float* wp = w + oc * 9;  // uniform -> s_load
    float s00 = 0.f, s01 = 0.f, s10 = 0.f, s11 = 0.f;
#pragma unroll
    for (int ky = 0; ky < 3; ++ky)
#pragma unroll
      for (int kx = 0; kx < 3; ++kx) {
        float wv = wp[ky * 3 + kx];
        s00 = fmaf(in[ky][kx], wv, s00);
        s01 = fmaf(in[ky][kx + 1], wv, s01);
        s10 = fmaf(in[ky + 1][kx], wv, s10);
        s11 = fmaf(in[ky + 1][kx + 1], wv, s11);
      }
    float m = fmaxf(fmaxf(s00, s01), fmaxf(s10, s11)) + bias[oc];
    op[oc * 16384] = GELU(m);
  }
}

// ---------------- Kernel B: conv2 (16->32) + maxpool2 --------------------------
// Ping-pong iv tile across ic: issue ic+1's ds_reads before ic's 72-FMA block so
// the ds_read latency hides under FMAs (counted lgkmcnt instead of load-use stall).
__device__ __forceinline__ void e2_loadiv(float (&dst)[4][4], const float* t) {
#pragma unroll
  for (int dy = 0; dy < 4; ++dy)
#pragma unroll
    for (int dx = 0; dx < 4; ++dx)
      dst[dy][dx] = t[dy * 20 + (dx & 1) * 10 + (dx >> 1)];
}
__device__ __forceinline__ void e2_fma(float (&acc)[4][8], const float (&iv)[4][4],
                                       const float* wp) {
#pragma unroll
  for (int k = 0; k < 9; ++k) {
    int ky = k / 3, kx = k % 3;
#pragma unroll
    for (int o = 0; o < 8; ++o) {
      float wv = wp[k * 8 + o];
      acc[0][o] = fmaf(iv[ky][kx], wv, acc[0][o]);
      acc[1][o] = fmaf(iv[ky][kx + 1], wv, acc[1][o]);
      acc[2][o] = fmaf(iv[ky + 1][kx], wv, acc[2][o]);
      acc[3][o] = fmaf(iv[ky + 1][kx + 1], wv, acc[3][o]);
    }
  }
}
__global__ __launch_bounds__(256) void k_enc2(const float* __restrict__ h1,
                                              const float* __restrict__ fwe2,
                                              const float* __restrict__ bias,
                                              float* __restrict__ h2) {
  __shared__ float st[16 * 360];  // [ic][18 rows][20: evens 0-9, odds 10-19]
  int tid = threadIdx.x;
  int b = blockIdx.y;
  int Y0 = (blockIdx.x >> 3) * 8, X0 = (blockIdx.x & 7) * 8;
  int r_s = 2 * Y0 - 1, c_s = 2 * X0 - 1;
  const float* ip = h1 + (size_t)b * 262144;
  for (int i = tid; i < 5184; i += 256) {  // 16 ic x 18 x 18
    int ic = i / 324, rr = (i % 324) / 18, cc = i % 18;
    int r = r_s + rr, c = c_s + cc;
    float v = ((unsigned)r < 128u && (unsigned)c < 128u) ? ip[ic * 16384 + r * 128 + c] : 0.f;
    st[ic * 360 + rr * 20 + (cc & 1) * 10 + (cc >> 1)] = v;
  }
  __syncthreads();
  int lane = tid & 63;
  int grp = __builtin_amdgcn_readfirstlane(tid >> 6);
  int oc0 = grp * 8;
  int ty = lane >> 3, tx = lane & 7;
  float acc[4][8];
#pragma unroll
  for (int p = 0; p < 4; ++p)
#pragma unroll
    for (int o = 0; o < 8; ++o) acc[p][o] = 0.f;
  const float* wgrp = fwe2 + grp * 1152;  // scalar base
  const float* tb = st + (2 * ty) * 20 + tx;
  float ivA[4][4], ivB[4][4];
  e2_loadiv(ivA, tb);
#pragma unroll 1
  for (int ic = 0; ic < 16; ic += 2) {
    e2_loadiv(ivB, tb + (ic + 1) * 360);
    e2_fma(acc, ivA, wgrp + ic * 72);
    e2_loadiv(ivA, tb + ((ic + 2) & 15) * 360);  // wrap: harmless re-read
    e2_fma(acc, ivB, wgrp + (ic + 1) * 72);
  }
  float* op = h2 + (size_t)b * 131072 + (Y0 + ty) * 64 + X0 + tx;
#pragma unroll
  for (int o = 0; o < 8; ++o) {
    float m = fmaxf(fmaxf(acc[0][o], acc[1][o]), fmaxf(acc[2][o], acc[3][o])) + bias[oc0 + o];
    op[(oc0 + o) * 4096] = m;
  }
}

// ---------------- Kernel C1: VQ distance scan over a 128-code chunk ------------
// 4 tokens/thread: one codebook row (32 scalar loads + 1 lgkm drain) now feeds
// 128 FMAs (~256 cyc of cover vs ~200 cy SMEM latency) -> drains amortized 4x.
// Tokens pinned in VGPRs via opaque asm loads (cannot be rematerialized).
// Grid: 4 chunks x 128 blocks = 512 blocks = 2 blocks/CU; ILP covers latency.
#define VQLOAD(R, CSQv, JN)                                                    \
  {                                                                            \
    const float* nb = rb + (size_t)(JN) * 32;                                  \
    _Pragma("unroll") for (int q = 0; q < 32; ++q) R[q] = nb[q];               \
    CSQv = scsq[(JN)];                                                         \
  }
#define VQSTEP(R, CSQ, JV)                                                     \
  {                                                                            \
    float s00 = 0, s01 = 0, s10 = 0, s11 = 0, s20 = 0, s21 = 0, s30 = 0,       \
          s31 = 0;                                                             \
    _Pragma("unroll") for (int q = 0; q < 32; q += 2) {                        \
      s00 = fmaf(R[q], f[0][q], s00);  s01 = fmaf(R[q + 1], f[0][q + 1], s01); \
      s10 = fmaf(R[q], f[1][q], s10);  s11 = fmaf(R[q + 1], f[1][q + 1], s11); \
      s20 = fmaf(R[q], f[2][q], s20);  s21 = fmaf(R[q + 1], f[2][q + 1], s21); \
      s30 = fmaf(R[q], f[3][q], s30);  s31 = fmaf(R[q + 1], f[3][q + 1], s31); \
    }                                                                          \
    float d0 = (CSQ)-2.f * (s00 + s01); if (d0 < best0) { best0 = d0; bi0 = (JV); } \
    float d1 = (CSQ)-2.f * (s10 + s11); if (d1 < best1) { best1 = d1; bi1 = (JV); } \
    float d2 = (CSQ)-2.f * (s20 + s21); if (d2 < best2) { best2 = d2; bi2 = (JV); } \
    float d3 = (CSQ)-2.f * (s30 + s31); if (d3 < best3) { best3 = d3; bi3 = (JV); } \
  }
__global__ __launch_bounds__(256, 2) void k_vq_chunk(const float* __restrict__ h2,
                                                     const float* __restrict__ cb,
                                                     float* __restrict__ dists,
                                                     int* __restrict__ idxs) {
  __shared__ float scsq[128];
  int tid = threadIdx.x;
  int chunk = blockIdx.x >> 7;
  int jbase = chunk << 7;
  if (tid < 128) {
    const float* row = cb + (size_t)(jbase + tid) * 32;
    float s = 0.f;
#pragma unroll
    for (int d = 0; d < 32; ++d) s = fmaf(row[d], row[d], s);
    scsq[tid] = s;
  }
  int gid = (blockIdx.x & 127) * 256 + tid;  // [0, 32768)
  float f[4][32];
#pragma unroll
  for (int k = 0; k < 4; ++k) {
    int t = gid + k * 32768;
    const float* p = h2 + (size_t)(t >> 12) * 131072 + (t & 4095);
#pragma unroll
    for (int c = 0; c < 32; ++c)
      asm volatile("global_load_dword %0, %1, off"
                   : "=v"(f[k][c])
                   : "v"(p + (size_t)c * 4096));
  }
  __syncthreads();
  asm volatile("s_waitcnt vmcnt(0)" ::: "memory");
  __builtin_amdgcn_sched_barrier(0);

  float best0 = 3.4e38f, best1 = 3.4e38f, best2 = 3.4e38f, best3 = 3.4e38f;
  int bi0 = jbase, bi1 = jbase, bi2 = jbase, bi3 = jbase;
  const float* rb = cb + (size_t)jbase * 32;
  float A[32], B[32], csqA, csqB;
  VQLOAD(A, csqA, 0);
#pragma unroll 1
  for (int jl = 0; jl < 128; jl += 2) {
    VQLOAD(B, csqB, jl + 1);
    VQSTEP(A, csqA, jbase + jl);
    VQLOAD(A, csqA, (jl + 2) & 127);  // wrap: stays in-bounds
    VQSTEP(B, csqB, jbase + jl + 1);
  }
  size_t cbase = (size_t)chunk * 131072;
  dists[cbase + gid] = best0;           idxs[cbase + gid] = bi0;
  dists[cbase + gid + 32768] = best1;   idxs[cbase + gid + 32768] = bi1;
  dists[cbase + gid + 65536] = best2;   idxs[cbase + gid + 65536] = bi2;
  dists[cbase + gid + 98304] = best3;   idxs[cbase + gid + 98304] = bi3;
}

// ---------------- Kernel C2: merge 4 chunk candidates, quantize, loss ----------
__global__ __launch_bounds__(256) void k_vq_merge(float* __restrict__ h2,
                                                  const float* __restrict__ cb,
                                                  const float* __restrict__ dists,
                                                  const int* __restrict__ idxs,
                                                  float* __restrict__ idxout,
                                                  float* __restrict__ partial) {
  __shared__ float sred[4];
  int tid = threadIdx.x;
  int t = blockIdx.x * 256 + tid;
  float bd = dists[t];
  int bi = idxs[t];
#pragma unroll
  for (int k = 1; k < 4; ++k) {
    float dk = dists[(size_t)k * 131072 + t];
    int ik = idxs[(size_t)k * 131072 + t];
    if (dk < bd) { bd = dk; bi = ik; }
  }
  size_t a = (size_t)(t >> 12) * 131072 + (t & 4095);
  const float* q = cb + (size_t)bi * 32;
  float loss = 0.f;
#pragma unroll
  for (int c = 0; c < 32; ++c) {
    float f = h2[a + c * 4096];
    float qv = q[c];
    h2[a + c * 4096] = qv;
    float dd = qv - f;
    loss = fmaf(dd, dd, loss);
  }
  idxout[t] = (float)bi;
#pragma unroll
  for (int off = 32; off > 0; off >>= 1) loss += __shfl_down(loss, off, 64);
  if ((tid & 63) == 0) sred[tid >> 6] = loss;
  __syncthreads();
  if (tid == 0) partial[blockIdx.x] = (sred[0] + sred[1]) + (sred[2] + sred[3]);
}

// ---------------- Kernel F: finalize commit loss (512 partials) ----------------
__global__ __launch_bounds__(256) void k_loss(const float* __restrict__ partial,
                                              float* __restrict__ lossout) {
  __shared__ float sred[4];
  int tid = threadIdx.x;
  float v = partial[tid] + partial[tid + 256];
#pragma unroll
  for (int off = 32; off > 0; off >>= 1) v += __shfl_down(v, off, 64);
  if ((tid & 63) == 0) sred[tid >> 6] = v;
  __syncthreads();
  if (tid == 0)
    lossout[0] = ((sred[0] + sred[1]) + (sred[2] + sred[3])) * (1.0f / 4194304.0f);
}

// ---------------- Kernel D: up2 + conv (32->16) + gelu, phase-folded -----------
// Same ping-pong pipelining as enc2: i3 tile for ic+1 issued before ic's FMAs.
__device__ __forceinline__ void d1_loadi3(float (&dst)[3][3], const float* t) {
#pragma unroll
  for (int dy = 0; dy < 3; ++dy)
#pragma unroll
    for (int dx = 0; dx < 3; ++dx) dst[dy][dx] = t[dy * 20 + dx];
}
__device__ __forceinline__ void d1_fma(float (&acc)[4][8], const float (&i3)[3][3],
                                       const float* wp) {
#pragma unroll
  for (int p = 0; p < 4; ++p) {
    int a = p >> 1, b2 = p & 1;
#pragma unroll
    for (int tp = 0; tp < 4; ++tp) {
      int dy = tp >> 1, dx = tp & 1;
      float iv = i3[a + dy][b2 + dx];
#pragma unroll
      for (int o2 = 0; o2 < 8; ++o2)
        acc[p][o2] = fmaf(iv, wp[(p * 4 + tp) * 8 + o2], acc[p][o2]);
    }
  }
}
__global__ __launch_bounds__(256) void k_dec1(const float* __restrict__ q,
                                              const float* __restrict__ fwd1,
                                              const float* __restrict__ bias,
                                              float* __restrict__ o) {
  __shared__ float st[32 * 200];  // [ic][10 rows][20]
  int tid = threadIdx.x;
  int b = blockIdx.y;
  int R0 = (blockIdx.x >> 2) * 8, C0 = (blockIdx.x & 3) * 16;
  const float* ip = q + (size_t)b * 131072;
  for (int i = tid; i < 5760; i += 256) {  // 32 ic x 10 x 18
    int ic = i / 180, rr = (i % 180) / 18, cc = i % 18;
    int r = R0 - 1 + rr, c = C0 - 1 + cc;
    st[ic * 200 + rr * 20 + cc] =
        ((unsigned)r < 64u && (unsigned)c < 64u) ? ip[ic * 4096 + r * 64 + c] : 0.f;
  }
  __syncthreads();
  int lane = tid & 63, wid = tid >> 6;
  int qx = wid & 1;
  int grp = __builtin_amdgcn_readfirstlane(wid >> 1);
  int ty = lane >> 3, tx = qx * 8 + (lane & 7);
  float acc[4][8];
#pragma unroll
  for (int p = 0; p < 4; ++p)
#pragma unroll
    for (int o2 = 0; o2 < 8; ++o2) acc[p][o2] = 0.f;
  const float* wb = fwd1 + grp * 4096;
  const float* tb = st + ty * 20 + tx;
  float i3A[3][3], i3B[3][3];
  d1_loadi3(i3A, tb);
#pragma unroll 1
  for (int ic = 0; ic < 32; ic += 2) {
    d1_loadi3(i3B, tb + (ic + 1) * 200);
    d1_fma(acc, i3A, wb + ic * 128);
    d1_loadi3(i3A, tb + ((ic + 2) & 31) * 200);  // wrap: harmless re-read
    d1_fma(acc, i3B, wb + (ic + 1) * 128);
  }
  int Y = 2 * (R0 + ty), X = 2 * (C0 + tx);
#pragma unroll
  for (int o2 = 0; o2 < 8; ++o2) {
    int oc = grp * 8 + o2;
    float bb = bias[oc];
    float* p = o + (size_t)b * 262144 + (size_t)oc * 16384 + Y * 128 + X;
    float2 r0v, r1v;
    r0v.x = GELU(acc[0][o2] + bb);
    r0v.y = GELU(acc[1][o2] + bb);
    r1v.x = GELU(acc[2][o2] + bb);
    r1v.y = GELU(acc[3][o2] + bb);
    *(float2*)p = r0v;
    *(float2*)(p + 128) = r1v;
  }
}

// ---------------- Kernel E: up2 + conv (16->1) + clip, phase-folded ------------
__global__ __launch_bounds__(256) void k_dec2(const float* __restrict__ d1,
                                              const float* __restrict__ fwd2,
                                              const float* __restrict__ bias,
                                              float* __restrict__ out) {
  __shared__ float st[16 * 360];  // [ic][18 rows][20]
  int tid = threadIdx.x;
  int b = blockIdx.y;
  int R0 = (blockIdx.x >> 3) * 16, C0 = (blockIdx.x & 7) * 16;
  const float* ip = d1 + (size_t)b * 262144;
  for (int i = tid; i < 5184; i += 256) {  // 16 ic x 18 x 18
    int ic = i / 324, rr = (i % 324) / 18, cc = i % 18;
    int r = R0 - 1 + rr, c = C0 - 1 + cc;
    st[ic * 360 + rr * 20 + cc] =
        ((unsigned)r < 128u && (unsigned)c < 128u) ? ip[ic * 16384 + r * 128 + c] : 0.f;
  }
  __syncthreads();
  int lane = tid & 63, wid = tid >> 6;
  int qy = wid >> 1, qx = wid & 1;
  int ty = qy * 8 + (lane >> 3), tx = qx * 8 + (lane & 7);
  float acc[4] = {0.f, 0.f, 0.f, 0.f};
#pragma unroll 1
  for (int ic = 0; ic < 16; ++ic) {
    const float* t = st + ic * 360 + ty * 20 + tx;
    float i3[3][3];
#pragma unroll
    for (int dy = 0; dy < 3; ++dy)
#pragma unroll
      for (int dx = 0; dx < 3; ++dx) i3[dy][dx] = t[dy * 20 + dx];
    const float* wp = fwd2 + ic * 16;  // scalar loads
#pragma unroll
    for (int p = 0; p < 4; ++p) {
      int a = p >> 1, b2 = p & 1;
#pragma unroll
      for (int tp = 0; tp < 4; ++tp) {
        int dy = tp >> 1, dx = tp & 1;
        acc[p] = fmaf(i3[a + dy][b2 + dx], wp[p * 4 + tp], acc[p]);
      }
    }
  }
  float bv = bias[0];
  int Y = 2 * (R0 + ty), X = 2 * (C0 + tx);
  float* op = out + (size_t)b * 65536 + Y * 256 + X;
  float2 r0v, r1v;
  r0v.x = fminf(1.0f, fmaxf(-1.0f, acc[0] + bv));
  r0v.y = fminf(1.0f, fmaxf(-1.0f, acc[1] + bv));
  r1v.x = fminf(1.0f, fmaxf(-1.0f, acc[2] + bv));
  r1v.y = fminf(1.0f, fmaxf(-1.0f, acc[3] + bv));
  *(float2*)op = r0v;
  *(float2*)(op + 256) = r1v;
}

extern "C" void kernel_launch(void* const* d_in, const int* in_sizes, int n_in,
                              void* d_out, int out_size, void* d_ws, size_t ws_size,
                              hipStream_t stream) {
  const float* x   = (const float*)d_in[0];
  const float* e1w = (const float*)d_in[1];
  const float* e1b = (const float*)d_in[2];
  const float* e2w = (const float*)d_in[3];
  const float* e2b = (const float*)d_in[4];
  const float* cb  = (const float*)d_in[5];
  const float* d1w = (const float*)d_in[6];
  const float* d1b = (const float*)d_in[7];
  const float* d2w = (const float*)d_in[8];
  const float* d2b = (const float*)d_in[9];

  float* out = (float*)d_out;
  float* y       = out;                       // [32,1,256,256] = 2097152
  float* idxout  = out + 2097152;             // [32,64,64]     = 131072 (as float)
  float* lossout = out + 2097152 + 131072;    // scalar

  float* ws = (float*)d_ws;
  float* h1      = ws;                        // [32,16,128,128] = 8388608 floats
  float* h2      = ws + 8388608;              // [32,32,64,64]   = 4194304 floats
  float* partial = ws + 12582912;             // 512 floats
  float* fwe2    = ws + 12583424;             // 4608
  float* fwd1    = ws + 12588032;             // 8192
  float* fwd2    = ws + 12596224;             // 256
  // VQ chunk outputs reuse the (dead-after-enc2) h1 region:
  float* dists   = ws;                        // 4 x 131072 floats
  int*   idxs    = (int*)(ws + 524288);       // 4 x 131072 ints
  float* d1o     = h1;                        // dec1 output reuses h1 (after merge)

  k_fold<<<dim3(51), 256, 0, stream>>>(e2w, d1w, d2w, fwe2, fwd1, fwd2);
  k_enc1<<<dim3(2048), 256, 0, stream>>>(x, e1w, e1b, h1);
  k_enc2<<<dim3(64, 32), 256, 0, stream>>>(h1, fwe2, e2b, h2);
  k_vq_chunk<<<dim3(512), 256, 0, stream>>>(h2, cb, dists, idxs);
  k_vq_merge<<<dim3(512), 256, 0, stream>>>(h2, cb, dists, idxs, idxout, partial);
  k_loss<<<dim3(1), 256, 0, stream>>>(partial, lossout);
  k_dec1<<<dim3(32, 32), 256, 0, stream>>>(h2, fwd1, d1b, d1o);
  k_dec2<<<dim3(64, 32), 256, 0, stream>>>(d1o, fwd2, d2b, y);
}